// Round 7
// baseline (345.796 us; speedup 1.0000x reference)
//
#include <hip/hip_runtime.h>
#include <hip/hip_bf16.h>
#include <stdint.h>

// ---------- types ----------
typedef __bf16  bf16x8 __attribute__((ext_vector_type(8)));
typedef short   s16x8  __attribute__((ext_vector_type(8)));
typedef int     i32x4  __attribute__((ext_vector_type(4)));
typedef float   f32x4  __attribute__((ext_vector_type(4)));

union Frag { s16x8 s; bf16x8 b; i32x4 i; };

static __device__ __forceinline__ short f2bf(float f) {
    union { float f; unsigned u; } v; v.f = f;
    unsigned r = (v.u + 0x7FFFu + ((v.u >> 16) & 1u)) >> 16;   // RNE
    return (short)r;
}
static __device__ __forceinline__ float bf2f(short s) {
    union { unsigned u; float f; } v; v.u = ((unsigned)(unsigned short)s) << 16;
    return v.f;
}
static __device__ __forceinline__ float fast_rcp(float x) { return __builtin_amdgcn_rcpf(x); }
static __device__ __forceinline__ float tanh_fast(float x) {
    float e = __expf(-2.0f * x);
    return (1.0f - e) * fast_rcp(1.0f + e);
}
static __device__ __forceinline__ f32x4 mfma16(bf16x8 a, bf16x8 b, f32x4 c) {
    return __builtin_amdgcn_mfma_f32_16x16x32_bf16(a, b, c, 0, 0, 0);
}

// Barrier that does NOT drain vmcnt (LDS-visibility only).
static __device__ __forceinline__ void block_sync_lds() {
    asm volatile("s_waitcnt lgkmcnt(0)\n\ts_barrier" ::: "memory");
}

#define GLDS(gp, lp) __builtin_amdgcn_global_load_lds( \
    (const __attribute__((address_space(1))) void*)(gp), \
    (__attribute__((address_space(3))) void*)(lp), 16, 0, 0)

// Constants
#define TT 128
#define BB 2048
#define HH 64
#define FF 128
#define AA 15
#define CH 8
#define LOGITS_OFF 0
#define VF_OFF   3932160
#define HT_OFF   4194304
#define CT_OFF   4325376

// ---------------- helper-wave MLP pieces (op order identical to old enc: bit-exact y) ----------------
static __device__ __forceinline__ void xload(
    const float* __restrict__ x, int t_x, int b0, int lane, int q, f32x4* xr)
{
    const float* xp = x + ((size_t)t_x*BB + b0 + (lane & 7))*FF + 8*q;
#pragma unroll
    for (int kf = 0; kf < 4; ++kf) {
        xr[2*kf]   = *(const f32x4*)(xp + 32*kf);
        xr[2*kf+1] = *(const f32x4*)(xp + 32*kf + 4);
    }
}
static __device__ __forceinline__ void mlp_l1(
    const f32x4* xr, const float* b1v, const short (*w1t)[136],
    int c, int q, f32x4* acc1)
{
    Frag af[4];
#pragma unroll
    for (int kf = 0; kf < 4; ++kf)
#pragma unroll
        for (int jj = 0; jj < 4; ++jj) {
            af[kf].s[jj]   = f2bf(xr[2*kf][jj]);
            af[kf].s[4+jj] = f2bf(xr[2*kf+1][jj]);
        }
#pragma unroll
    for (int ct = 0; ct < 4; ++ct) acc1[ct] = (f32x4){b1v[ct], b1v[ct], b1v[ct], b1v[ct]};
#pragma unroll
    for (int kf = 0; kf < 4; ++kf)
#pragma unroll
        for (int ct = 0; ct < 4; ++ct) {
            Frag bf; bf.s = *(const s16x8*)&w1t[16*ct + c][32*kf + 8*q];
            acc1[ct] = mfma16(af[kf].b, bf.b, acc1[ct]);
        }
}
static __device__ __forceinline__ void mlp_mid(
    const f32x4* acc1, short (*c1)[72], int c, int q, Frag* a2f)
{
    if (q < 2)
#pragma unroll
        for (int ct = 0; ct < 4; ++ct)
#pragma unroll
            for (int i = 0; i < 4; ++i)
                c1[4*q + i][16*ct + c] = f2bf(tanh_fast(acc1[ct][i]));
    // same-wave LDS RAW (enc-proven pattern; compiler inserts lgkm waits)
    a2f[0].s = *(const s16x8*)&c1[c & 7][8*q];
    a2f[1].s = *(const s16x8*)&c1[c & 7][32 + 8*q];
}
static __device__ __forceinline__ void mlp_l2(
    const Frag* a2f, const float* b2v, const short (*w2t)[72],
    short (*yout)[72], int c, int q)
{
    f32x4 acc2[4];
#pragma unroll
    for (int ct = 0; ct < 4; ++ct) acc2[ct] = (f32x4){b2v[ct], b2v[ct], b2v[ct], b2v[ct]};
#pragma unroll
    for (int kf = 0; kf < 2; ++kf)
#pragma unroll
        for (int ct = 0; ct < 4; ++ct) {
            Frag bf; bf.s = *(const s16x8*)&w2t[16*ct + c][32*kf + 8*q];
            acc2[ct] = mfma16(a2f[kf].b, bf.b, acc2[ct]);
        }
    if (q < 2)
#pragma unroll
        for (int ct = 0; ct < 4; ++ct)
#pragma unroll
            for (int i = 0; i < 4; ++i)
                yout[4*q + i][16*ct + c] = f2bf(tanh_fast(acc2[ct][i]));
}

// ============================ fused MLP+LSTM+heads ============================
// 256 blocks x 512 thr, 8 batch rows/block, 16 chunks x 8 phases.
// Waves 0-3 (crit): register-gy LSTM step (unchanged, bit-exact).
// Waves 4-7 (helpers): during chunk tc compute chunk tc+1's y; x tiles are
// PREFETCHED one chunk ahead into double-buffered registers (xrA at tc.p3,
// xrB at tc.p5, consumed at tc+1.p1 / tc+1.p4 — 6-7 phase lead covers ~900cyc
// HBM latency; round-6's 1-phase lead was the stall). w4 flushes outputs at p7;
// head duty wave 4+(p&3) each step. No workspace, no second kernel.
__global__ __launch_bounds__(512, 1) void fused_kernel(
    const float* __restrict__ x, const float* __restrict__ done,
    const float* __restrict__ h0, const float* __restrict__ c0,
    const float* __restrict__ W1, const float* __restrict__ b1,
    const float* __restrict__ W2, const float* __restrict__ b2,
    const float* __restrict__ Wih, const float* __restrict__ bih,
    const float* __restrict__ Whh, const float* __restrict__ bhh,
    const float* __restrict__ Wa, const float* __restrict__ ba,
    const float* __restrict__ Wc, const float* __restrict__ bc,
    float* __restrict__ out_logits, float* __restrict__ out_vf,
    float* __restrict__ hT_out, float* __restrict__ cT_out)
{
    __shared__ short w1t[64][136];          // 17.4 KB W1^T bf16
    __shared__ short w2t[64][72];           // 9.2 KB  W2^T bf16
    __shared__ short ybuf[2][CH][8][72];    // 18.4 KB y tiles (row x col), chunk-parity dbuf
    __shared__ short c1buf[4][8][72];       // 4.6 KB  per-helper-wave L1 scratch
    __shared__ float obuf[2][CH][8][16];    // 8 KB    head outputs
    __shared__ short zbuf[2][8][72];        // 2.3 KB  unmasked h
    __shared__ short hbuf[2][8][72];        // 2.3 KB  masked h (scan state)
    __shared__ float dbuf[TT+1][8];         // 4.1 KB  done, +zero row

    const int tid  = threadIdx.x;
    const int lane = tid & 63;
    const int w    = tid >> 6;
    const int c    = lane & 15;
    const int q    = lane >> 4;
    const int blk  = blockIdx.x;
    const int b0   = blk * 8;
    const bool crit = (w < 4);
    const int hw   = w - 4;
    const int r0   = 4*(q & 1) + 2*(q >> 1);   // owned row pair

    // ---------------- per-role register state ----------------
    Frag  wf[4][2];      // crit: Whh B-frags
    Frag  wfi[4][2];     // crit: Wih B-frags
    float biasv[4];      // crit: bih+bhh
    Frag  hwf[2];        // helper: head B-frags
    float hbv = 0.f;     // helper: head bias
    float b1v[4] = {0,0,0,0}, b2v[4] = {0,0,0,0};   // helper: MLP biases
    float cst0 = 0.f, cst1 = 0.f;   // crit: c state
    f32x4 gyr[4];        // crit: running gate pre-activation
    f32x4 xrA[8], xrB[8];// helper: prefetched x tiles (dbl-buffered, 1-chunk lead)
    f32x4 acc1[4];       // helper: L1 accum (spans 1 phase)
    Frag  a2f[2];        // helper: L2 A-frags (spans 1 phase)

    // ---------------- prologue ----------------
    // all waves: stage W1/W2 to LDS (bf16, transposed)
    for (int i = tid; i < 128*64; i += 512) { int k = i >> 6, n = i & 63; w1t[n][k] = f2bf(W1[i]); }
    for (int i = tid; i < 64*64;  i += 512) { int k = i >> 6, n = i & 63; w2t[n][k] = f2bf(W2[i]); }

    if (crit) {
        const int jcol = 16*w + c;
#pragma unroll
        for (int a = 0; a < 4; ++a) {
            const int col = 64*a + jcol;
            biasv[a] = bih[col] + bhh[col];
#pragma unroll
            for (int kf = 0; kf < 2; ++kf) {
                const float* wp = Whh + (size_t)col*HH + 32*kf + 8*q;
                f32x4 w0 = *(const f32x4*)wp;
                f32x4 w1 = *(const f32x4*)(wp + 4);
#pragma unroll
                for (int jj = 0; jj < 4; ++jj) { wf[a][kf].s[jj] = f2bf(w0[jj]); wf[a][kf].s[4+jj] = f2bf(w1[jj]); }
                const float* vp = Wih + (size_t)col*HH + 32*kf + 8*q;
                f32x4 v0 = *(const f32x4*)vp;
                f32x4 v1 = *(const f32x4*)(vp + 4);
#pragma unroll
                for (int jj = 0; jj < 4; ++jj) { wfi[a][kf].s[jj] = f2bf(v0[jj]); wfi[a][kf].s[4+jj] = f2bf(v1[jj]); }
            }
        }
    } else {
        // stage done (32 steps per wave)
        {
            const int t0 = hw * 32;
            const float* gp = done + (size_t)(t0 + (lane >> 1))*BB + b0 + 4*(lane & 1);
            GLDS(gp, &dbuf[t0][0]);
        }
#pragma unroll
        for (int kf = 0; kf < 2; ++kf)
#pragma unroll
            for (int jj = 0; jj < 8; ++jj) {
                int k = 32*kf + 8*q + jj;
                hwf[kf].s[jj] = f2bf((c < 15) ? Wa[k*AA + c] : Wc[k]);
            }
        hbv = (c < 15) ? ba[c] : bc[0];
#pragma unroll
        for (int ct = 0; ct < 4; ++ct) { b1v[ct] = b1[16*ct + c]; b2v[ct] = b2[16*ct + c]; }
        // x loads for chunk-0's tiles (one-time startup stall is fine)
        xload(x, 2*hw + 0, b0, lane, q, xrA);
    }
    if (tid < 8) dbuf[TT][tid] = 0.0f;
    block_sync_lds();   // #1: w1t/w2t visible

    if (!crit) {
        // compute chunk 0 y (tiles 2hw, 2hw+1)
        mlp_l1(xrA, b1v, w1t, c, q, acc1);
        mlp_mid(acc1, c1buf[hw], c, q, a2f);
        mlp_l2(a2f, b2v, w2t, ybuf[0][2*hw + 0], c, q);
        xload(x, 2*hw + 1, b0, lane, q, xrA);
        mlp_l1(xrA, b1v, w1t, c, q, acc1);
        mlp_mid(acc1, c1buf[hw], c, q, a2f);
        mlp_l2(a2f, b2v, w2t, ybuf[0][2*hw + 1], c, q);
        // prefetch x for chunk-1's MLP (runs during main-loop chunk 0)
        xload(x, 8 + 2*hw + 0, b0, lane, q, xrA);
        xload(x, 8 + 2*hw + 1, b0, lane, q, xrB);
        __builtin_amdgcn_s_waitcnt(0x0F70);   // vmcnt(0): dbuf GLDS complete
    }
    block_sync_lds();   // #2: dbuf + ybuf[0] visible

    if (crit) {
        const int jcol = 16*w + c;
        {
            float d0 = dbuf[0][r0 + 0];
            float d1 = dbuf[0][r0 + 1];
            float cv0 = c0[(size_t)(b0 + r0 + 0)*HH + jcol];
            float cv1 = c0[(size_t)(b0 + r0 + 1)*HH + jcol];
            cst0 = (d0 != 0.0f) ? 0.0f : cv0;
            cst1 = (d1 != 0.0f) ? 0.0f : cv1;
        }
        if (tid < 128) {
            int mm = tid & 7, j4 = (tid >> 3) & 15;
            float dm = dbuf[0][mm];
            f32x4 hv = *(const f32x4*)(h0 + (size_t)(b0 + mm)*HH + 4*j4);
#pragma unroll
            for (int ii = 0; ii < 4; ++ii)
                hbuf[0][mm][4*j4 + ii] = (dm != 0.0f) ? (short)0 : f2bf(hv[ii]);
        }
        // gy[0] = bias + y0@Wih^T
        {
            Frag yc0, yc1;
            yc0.s = *(const s16x8*)&ybuf[0][0][lane & 7][8*q];
            yc1.s = *(const s16x8*)&ybuf[0][0][lane & 7][32 + 8*q];
#pragma unroll
            for (int a = 0; a < 4; ++a) {
                f32x4 g = (f32x4){biasv[a], biasv[a], biasv[a], biasv[a]};
                g = mfma16(yc0.b, wfi[a][0].b, g);
                g = mfma16(yc1.b, wfi[a][1].b, g);
                gyr[a] = g;
            }
        }
    }
    block_sync_lds();   // #3: hbuf[0] visible

    // ---------------- main loop: 16 chunks x 8 phases ----------------
    for (int tc = 0; tc < 16; ++tc) {
#pragma unroll
        for (int p = 0; p < 8; ++p) {
            const int t = 8*tc + p;
            if (crit) {
                const int jcol = 16*w + c;
                const int cur = p & 1;
                Frag hf0, hf1;
                hf0.s = *(const s16x8*)&hbuf[cur][lane & 7][8*q];
                hf1.s = *(const s16x8*)&hbuf[cur][lane & 7][32 + 8*q];
                f32x4 acc[4];
#pragma unroll
                for (int a = 0; a < 4; ++a) {
                    acc[a] = mfma16(hf0.b, wf[a][0].b, gyr[a]);
                    acc[a] = mfma16(hf1.b, wf[a][1].b, acc[a]);
                }
                const bool hiq = (q >= 2);
                float g0[4], g1[4];
#pragma unroll
                for (int a = 0; a < 4; ++a) {
                    g0[a] = hiq ? acc[a][2] : acc[a][0];
                    g1[a] = hiq ? acc[a][3] : acc[a][1];
                }
                const float dn0 = dbuf[t+1][r0 + 0];
                const float dn1 = dbuf[t+1][r0 + 1];
                // gy[t+1] refill (hides under ELEM on MFMA pipe)
                if (tc < 15 || p < 7) {
                    const int ch = (p < 7) ? (tc & 1) : ((tc + 1) & 1);
                    const int sl = (p + 1) & 7;
                    Frag yc0, yc1;
                    yc0.s = *(const s16x8*)&ybuf[ch][sl][lane & 7][8*q];
                    yc1.s = *(const s16x8*)&ybuf[ch][sl][lane & 7][32 + 8*q];
#pragma unroll
                    for (int a = 0; a < 4; ++a) {
                        f32x4 g = (f32x4){biasv[a], biasv[a], biasv[a], biasv[a]};
                        g = mfma16(yc0.b, wfi[a][0].b, g);
                        g = mfma16(yc1.b, wfi[a][1].b, g);
                        gyr[a] = g;
                    }
                }
#define ELEM(GV, CSTV, RI, DN) {                                        \
                float ei = __expf(-GV[0]), ef = __expf(-GV[1]);         \
                float eg = __expf(-2.0f*GV[2]), eo = __expf(-GV[3]);    \
                float term = (1.0f - eg) * fast_rcp((1.0f + ei)*(1.0f + eg)); \
                float cn = fast_rcp(1.0f + ef)*CSTV + term;             \
                float ec = __expf(-2.0f*cn);                            \
                float hv = (1.0f - ec) * fast_rcp((1.0f + eo)*(1.0f + ec)); \
                short zb = f2bf(hv);                                    \
                zbuf[cur][RI][jcol] = zb;                               \
                const bool d = ((DN) != 0.0f);                          \
                CSTV = d ? 0.0f : cn;                                   \
                hbuf[cur ^ 1][RI][jcol] = d ? (short)0 : zb; }
                ELEM(g0, cst0, r0 + 0, dn0)
                ELEM(g1, cst1, r0 + 1, dn1)
#undef ELEM
            } else {
                // ---- helper MLP pipeline for chunk tc+1 (x prefetched last chunk) ----
                if (p == 1 && tc < 15) mlp_l1(xrA, b1v, w1t, c, q, acc1);
                if (p == 2 && tc < 15) mlp_mid(acc1, c1buf[hw], c, q, a2f);
                if (p == 3 && tc < 15) {
                    if (tc <= 13) xload(x, 8*(tc+2) + 2*hw + 0, b0, lane, q, xrA); // issue early
                    mlp_l2(a2f, b2v, w2t, ybuf[(tc+1) & 1][2*hw + 0], c, q);
                }
                if (p == 4 && tc < 15) mlp_l1(xrB, b1v, w1t, c, q, acc1);
                if (p == 5 && tc < 15) {
                    if (tc <= 13) xload(x, 8*(tc+2) + 2*hw + 1, b0, lane, q, xrB); // issue early
                    mlp_mid(acc1, c1buf[hw], c, q, a2f);
                }
                if (p == 6 && tc < 15) mlp_l2(a2f, b2v, w2t, ybuf[(tc+1) & 1][2*hw + 1], c, q);
                // ---- output flush (chunk tc-1) on w4's idle phase ----
                if (p == 7 && tc >= 1 && w == 4) {
                    const int cc = tc - 1;
                    const int s = lane >> 3, r = lane & 7;
                    const size_t row = (size_t)(8*cc + s)*BB + b0 + r;
                    const float* ob = &obuf[cc & 1][s][r][0];
                    float* lp = out_logits + row*AA;
#pragma unroll
                    for (int n = 0; n < 15; ++n) lp[n] = ob[n];
                    out_vf[row] = ob[15];
                }
                // ---- head duty for z[t-1] ----
                if ((tc > 0 || p > 0) && w == 4 + (p & 3)) {
                    const int tp = t - 1;
                    Frag zf0, zf1;
                    zf0.s = *(const s16x8*)&zbuf[tp & 1][lane & 7][8*q];
                    zf1.s = *(const s16x8*)&zbuf[tp & 1][lane & 7][32 + 8*q];
                    f32x4 ha = (f32x4){hbv, hbv, hbv, hbv};
                    ha = mfma16(zf0.b, hwf[0].b, ha);
                    ha = mfma16(zf1.b, hwf[1].b, ha);
                    if (q < 2) {
#pragma unroll
                        for (int i = 0; i < 4; ++i)
                            obuf[(tp >> 3) & 1][tp & 7][4*q + i][c] = ha[i];
                    }
                }
            }
            block_sync_lds();
        }
    }

    // ---------------- epilogue ----------------
    if (!crit && w == 7) {                         // head for z[127]
        Frag zf0, zf1;
        zf0.s = *(const s16x8*)&zbuf[1][lane & 7][8*q];
        zf1.s = *(const s16x8*)&zbuf[1][lane & 7][32 + 8*q];
        f32x4 ha = (f32x4){hbv, hbv, hbv, hbv};
        ha = mfma16(zf0.b, hwf[0].b, ha);
        ha = mfma16(zf1.b, hwf[1].b, ha);
        if (q < 2) {
#pragma unroll
            for (int i = 0; i < 4; ++i) obuf[1][7][4*q + i][c] = ha[i];
        }
    }
    __syncthreads();
    if (!crit && w == 4) {                         // flush chunk 15
        const int s = lane >> 3, r = lane & 7;
        const size_t row = (size_t)(120 + s)*BB + b0 + r;
        const float* ob = &obuf[1][s][r][0];
        float* lp = out_logits + row*AA;
#pragma unroll
        for (int n = 0; n < 15; ++n) lp[n] = ob[n];
        out_vf[row] = ob[15];
    }
    if (tid < 128) {                               // hT = z127
        int mm = tid & 7, j4 = (tid >> 3) & 15;
        f32x4 hv;
#pragma unroll
        for (int ii = 0; ii < 4; ++ii) hv[ii] = bf2f(zbuf[1][mm][4*j4 + ii]);
        *(f32x4*)(hT_out + (size_t)(b0 + mm)*HH + 4*j4) = hv;
    }
    if (crit) {
        const int jcol = 16*w + c;
        cT_out[(size_t)(b0 + r0 + 0)*HH + jcol] = cst0;
        cT_out[(size_t)(b0 + r0 + 1)*HH + jcol] = cst1;
    }
}

// ============================ launch ============================
extern "C" void kernel_launch(void* const* d_in, const int* in_sizes, int n_in,
                              void* d_out, int out_size, void* d_ws, size_t ws_size,
                              hipStream_t stream) {
    const float* x    = (const float*)d_in[0];
    const float* done = (const float*)d_in[1];
    const float* h0   = (const float*)d_in[2];
    const float* c0   = (const float*)d_in[3];
    const float* W1   = (const float*)d_in[4];
    const float* b1   = (const float*)d_in[5];
    const float* W2   = (const float*)d_in[6];
    const float* b2   = (const float*)d_in[7];
    const float* Wih  = (const float*)d_in[8];
    const float* bih  = (const float*)d_in[9];
    const float* Whh  = (const float*)d_in[10];
    const float* bhh  = (const float*)d_in[11];
    const float* Wa   = (const float*)d_in[12];
    const float* ba   = (const float*)d_in[13];
    const float* Wc   = (const float*)d_in[14];
    const float* bc   = (const float*)d_in[15];
    float* out = (float*)d_out;

    (void)d_ws; (void)ws_size;   // no workspace: fused single-kernel pipeline

    fused_kernel<<<256, 512, 0, stream>>>(x, done, h0, c0, W1, b1, W2, b2,
                                          Wih, bih, Whh, bhh, Wa, ba, Wc, bc,
                                          out + LOGITS_OFF, out + VF_OFF,
                                          out + HT_OFF, out + CT_OFF);
}

// Round 8
// 285.790 us; speedup vs baseline: 1.2100x; 1.2100x over previous
//
#include <hip/hip_runtime.h>
#include <hip/hip_bf16.h>
#include <stdint.h>

// ---------- types ----------
typedef __bf16  bf16x8 __attribute__((ext_vector_type(8)));
typedef short   s16x8  __attribute__((ext_vector_type(8)));
typedef int     i32x4  __attribute__((ext_vector_type(4)));
typedef float   f32x4  __attribute__((ext_vector_type(4)));

union Frag { s16x8 s; bf16x8 b; i32x4 i; };

static __device__ __forceinline__ short f2bf(float f) {
    union { float f; unsigned u; } v; v.f = f;
    unsigned r = (v.u + 0x7FFFu + ((v.u >> 16) & 1u)) >> 16;   // RNE
    return (short)r;
}
static __device__ __forceinline__ float bf2f(short s) {
    union { unsigned u; float f; } v; v.u = ((unsigned)(unsigned short)s) << 16;
    return v.f;
}
static __device__ __forceinline__ float fast_rcp(float x) { return __builtin_amdgcn_rcpf(x); }
static __device__ __forceinline__ float tanh_fast(float x) {
    float e = __expf(-2.0f * x);
    return (1.0f - e) * fast_rcp(1.0f + e);
}
static __device__ __forceinline__ f32x4 mfma16(bf16x8 a, bf16x8 b, f32x4 c) {
    return __builtin_amdgcn_mfma_f32_16x16x32_bf16(a, b, c, 0, 0, 0);
}

// Barrier that does NOT drain vmcnt (LDS-visibility only).
static __device__ __forceinline__ void block_sync_lds() {
    asm volatile("s_waitcnt lgkmcnt(0)\n\ts_barrier" ::: "memory");
}

#define GLDS(gp, lp) __builtin_amdgcn_global_load_lds( \
    (const __attribute__((address_space(1))) void*)(gp), \
    (__attribute__((address_space(3))) void*)(lp), 16, 0, 0)

// Constants
#define TT 128
#define BB 2048
#define HH 64
#define FF 128
#define AA 15
#define CH 8
#define LOGITS_OFF 0
#define VF_OFF   3932160
#define HT_OFF   4194304
#define CT_OFF   4325376

// ---------------- x staging: global_load_lds with XOR-swizzled SOURCE ----------------
// LDS tile layout: [8 rows][128 f32], 16B chunk k of row r holds global chunk (k ^ (r&7)).
// GLDS writes linearly (uniform LDS base + lane*16); the swizzle lives in the per-lane
// GLOBAL address (G21: both-sides-or-neither). Read side applies the same XOR ->
// conflict-free fragment reads (plain row-major would be 8-way on bank 4k).
static __device__ __forceinline__ void stage_x(
    const float* __restrict__ x, int t_x, int b0, int lane, float* dst)
{
    const int rh = lane >> 5;          // row within 1KB call: 2j + rh
    const int k  = lane & 31;          // 16B chunk within row
#pragma unroll
    for (int j = 0; j < 4; ++j) {
        const int row = 2*j + rh;
        const float* gp = x + ((size_t)t_x*BB + b0 + row)*FF + ((k ^ row) << 2);
        GLDS(gp, dst + j*256);
    }
}

// ---------------- helper-wave MLP pieces (dataflow identical to enc: bit-exact y) ----------------
static __device__ __forceinline__ void mlp_l1(
    const float* xt /* swizzled LDS tile [8][128] */, const float* b1v,
    const short (*w1t)[136], int lane, int c, int q, f32x4* acc1)
{
    const int row = lane & 7;
    Frag af[4];
#pragma unroll
    for (int kf = 0; kf < 4; ++kf) {
        const int k0 = 8*kf + 2*q;
        f32x4 x0 = *(const f32x4*)&xt[row*128 + (((k0    ) ^ row) << 2)];
        f32x4 x1 = *(const f32x4*)&xt[row*128 + (((k0 + 1) ^ row) << 2)];
#pragma unroll
        for (int jj = 0; jj < 4; ++jj) {
            af[kf].s[jj]   = f2bf(x0[jj]);
            af[kf].s[4+jj] = f2bf(x1[jj]);
        }
    }
#pragma unroll
    for (int ct = 0; ct < 4; ++ct) acc1[ct] = (f32x4){b1v[ct], b1v[ct], b1v[ct], b1v[ct]};
#pragma unroll
    for (int kf = 0; kf < 4; ++kf)
#pragma unroll
        for (int ct = 0; ct < 4; ++ct) {
            Frag bf; bf.s = *(const s16x8*)&w1t[16*ct + c][32*kf + 8*q];
            acc1[ct] = mfma16(af[kf].b, bf.b, acc1[ct]);
        }
}
static __device__ __forceinline__ void mlp_mid(
    const f32x4* acc1, short (*c1)[72], int c, int q, Frag* a2f)
{
    if (q < 2)
#pragma unroll
        for (int ct = 0; ct < 4; ++ct)
#pragma unroll
            for (int i = 0; i < 4; ++i)
                c1[4*q + i][16*ct + c] = f2bf(tanh_fast(acc1[ct][i]));
    // same-wave LDS RAW (enc-proven pattern; compiler inserts lgkm waits)
    a2f[0].s = *(const s16x8*)&c1[c & 7][8*q];
    a2f[1].s = *(const s16x8*)&c1[c & 7][32 + 8*q];
}
static __device__ __forceinline__ void mlp_l2(
    const Frag* a2f, const float* b2v, const short (*w2t)[72],
    short (*yout)[72], int c, int q)
{
    f32x4 acc2[4];
#pragma unroll
    for (int ct = 0; ct < 4; ++ct) acc2[ct] = (f32x4){b2v[ct], b2v[ct], b2v[ct], b2v[ct]};
#pragma unroll
    for (int kf = 0; kf < 2; ++kf)
#pragma unroll
        for (int ct = 0; ct < 4; ++ct) {
            Frag bf; bf.s = *(const s16x8*)&w2t[16*ct + c][32*kf + 8*q];
            acc2[ct] = mfma16(a2f[kf].b, bf.b, acc2[ct]);
        }
    if (q < 2)
#pragma unroll
        for (int ct = 0; ct < 4; ++ct)
#pragma unroll
            for (int i = 0; i < 4; ++i)
                yout[4*q + i][16*ct + c] = f2bf(tanh_fast(acc2[ct][i]));
}

// ============================ fused MLP+LSTM+heads ============================
// 256 blocks x 512 thr, 8 batch rows/block, 16 chunks x 8 phases.
// Waves 0-3 (crit): register-gy LSTM step (unchanged, bit-exact).
// Waves 4-7 (helpers): during chunk tc compute chunk tc+1's y from LDS xbuf;
// x tiles for chunk tc+2 are staged via global_load_lds at tc.p0 (2-chunk, 7-phase
// lead covers HBM latency) and drained once at tc.p7. NO x register buffers —
// round-6/7's xr registers spilled to scratch (WRITE_SIZE 23.8/53.5 MB vs 17.4).
// w4 flushes outputs at p7; head duty wave 4+(p&3) each step. No workspace.
__global__ __launch_bounds__(512, 1) void fused_kernel(
    const float* __restrict__ x, const float* __restrict__ done,
    const float* __restrict__ h0, const float* __restrict__ c0,
    const float* __restrict__ W1, const float* __restrict__ b1,
    const float* __restrict__ W2, const float* __restrict__ b2,
    const float* __restrict__ Wih, const float* __restrict__ bih,
    const float* __restrict__ Whh, const float* __restrict__ bhh,
    const float* __restrict__ Wa, const float* __restrict__ ba,
    const float* __restrict__ Wc, const float* __restrict__ bc,
    float* __restrict__ out_logits, float* __restrict__ out_vf,
    float* __restrict__ hT_out, float* __restrict__ cT_out)
{
    __shared__ float xbuf[2][CH][8][128];   // 64 KB  staged x tiles (swizzled), dbl-buf
    __shared__ short w1t[64][136];          // 17.4 KB W1^T bf16
    __shared__ short w2t[64][72];           // 9.2 KB  W2^T bf16
    __shared__ short ybuf[2][CH][8][72];    // 18.4 KB y tiles, chunk-parity dbuf
    __shared__ short c1buf[4][8][72];       // 4.6 KB  per-helper-wave L1 scratch
    __shared__ float obuf[2][CH][8][16];    // 8 KB    head outputs
    __shared__ short zbuf[2][8][72];        // 2.3 KB  unmasked h
    __shared__ short hbuf[2][8][72];        // 2.3 KB  masked h (scan state)
    __shared__ float dbuf[TT+1][8];         // 4.1 KB  done, +zero row

    const int tid  = threadIdx.x;
    const int lane = tid & 63;
    const int w    = tid >> 6;
    const int c    = lane & 15;
    const int q    = lane >> 4;
    const int blk  = blockIdx.x;
    const int b0   = blk * 8;
    const bool crit = (w < 4);
    const int hw   = w - 4;
    const int r0   = 4*(q & 1) + 2*(q >> 1);   // owned row pair

    // ---------------- per-role register state ----------------
    Frag  wf[4][2];      // crit: Whh B-frags
    Frag  wfi[4][2];     // crit: Wih B-frags
    float biasv[4];      // crit: bih+bhh
    Frag  hwf[2];        // helper: head B-frags
    float hbv = 0.f;     // helper: head bias
    float b1v[4] = {0,0,0,0}, b2v[4] = {0,0,0,0};   // helper: MLP biases
    float cst0 = 0.f, cst1 = 0.f;   // crit: c state
    f32x4 gyr[4];        // crit: running gate pre-activation
    f32x4 acc1[4];       // helper: L1 accum (spans 1 phase)
    Frag  a2f[2];        // helper: L2 A-frags (spans 1 phase)

    // ---------------- prologue ----------------
    // all waves: stage W1/W2 to LDS (bf16, transposed)
    for (int i = tid; i < 128*64; i += 512) { int k = i >> 6, n = i & 63; w1t[n][k] = f2bf(W1[i]); }
    for (int i = tid; i < 64*64;  i += 512) { int k = i >> 6, n = i & 63; w2t[n][k] = f2bf(W2[i]); }

    if (crit) {
        const int jcol = 16*w + c;
#pragma unroll
        for (int a = 0; a < 4; ++a) {
            const int col = 64*a + jcol;
            biasv[a] = bih[col] + bhh[col];
#pragma unroll
            for (int kf = 0; kf < 2; ++kf) {
                const float* wp = Whh + (size_t)col*HH + 32*kf + 8*q;
                f32x4 w0 = *(const f32x4*)wp;
                f32x4 w1 = *(const f32x4*)(wp + 4);
#pragma unroll
                for (int jj = 0; jj < 4; ++jj) { wf[a][kf].s[jj] = f2bf(w0[jj]); wf[a][kf].s[4+jj] = f2bf(w1[jj]); }
                const float* vp = Wih + (size_t)col*HH + 32*kf + 8*q;
                f32x4 v0 = *(const f32x4*)vp;
                f32x4 v1 = *(const f32x4*)(vp + 4);
#pragma unroll
                for (int jj = 0; jj < 4; ++jj) { wfi[a][kf].s[jj] = f2bf(v0[jj]); wfi[a][kf].s[4+jj] = f2bf(v1[jj]); }
            }
        }
    } else {
        // stage done (32 steps per wave) + x for chunks 0 and 1 (GLDS, LDS-direct)
        {
            const int t0 = hw * 32;
            const float* gp = done + (size_t)(t0 + (lane >> 1))*BB + b0 + 4*(lane & 1);
            GLDS(gp, &dbuf[t0][0]);
        }
#pragma unroll
        for (int i = 0; i < 2; ++i) {
            stage_x(x,     2*hw + i, b0, lane, &xbuf[0][2*hw + i][0][0]);
            stage_x(x, 8 + 2*hw + i, b0, lane, &xbuf[1][2*hw + i][0][0]);
        }
#pragma unroll
        for (int kf = 0; kf < 2; ++kf)
#pragma unroll
            for (int jj = 0; jj < 8; ++jj) {
                int k = 32*kf + 8*q + jj;
                hwf[kf].s[jj] = f2bf((c < 15) ? Wa[k*AA + c] : Wc[k]);
            }
        hbv = (c < 15) ? ba[c] : bc[0];
#pragma unroll
        for (int ct = 0; ct < 4; ++ct) { b1v[ct] = b1[16*ct + c]; b2v[ct] = b2[16*ct + c]; }
    }
    if (tid < 8) dbuf[TT][tid] = 0.0f;
    block_sync_lds();   // #1: w1t/w2t visible

    if (!crit) {
        __builtin_amdgcn_s_waitcnt(0x0F70);   // vmcnt(0): dbuf + xbuf[0]/[1] arrived
        // compute chunk 0 y (tiles 2hw, 2hw+1)
        mlp_l1(&xbuf[0][2*hw + 0][0][0], b1v, w1t, lane, c, q, acc1);
        mlp_mid(acc1, c1buf[hw], c, q, a2f);
        mlp_l2(a2f, b2v, w2t, ybuf[0][2*hw + 0], c, q);
        mlp_l1(&xbuf[0][2*hw + 1][0][0], b1v, w1t, lane, c, q, acc1);
        mlp_mid(acc1, c1buf[hw], c, q, a2f);
        mlp_l2(a2f, b2v, w2t, ybuf[0][2*hw + 1], c, q);
    }
    block_sync_lds();   // #2: dbuf + ybuf[0] visible

    if (crit) {
        const int jcol = 16*w + c;
        {
            float d0 = dbuf[0][r0 + 0];
            float d1 = dbuf[0][r0 + 1];
            float cv0 = c0[(size_t)(b0 + r0 + 0)*HH + jcol];
            float cv1 = c0[(size_t)(b0 + r0 + 1)*HH + jcol];
            cst0 = (d0 != 0.0f) ? 0.0f : cv0;
            cst1 = (d1 != 0.0f) ? 0.0f : cv1;
        }
        if (tid < 128) {
            int mm = tid & 7, j4 = (tid >> 3) & 15;
            float dm = dbuf[0][mm];
            f32x4 hv = *(const f32x4*)(h0 + (size_t)(b0 + mm)*HH + 4*j4);
#pragma unroll
            for (int ii = 0; ii < 4; ++ii)
                hbuf[0][mm][4*j4 + ii] = (dm != 0.0f) ? (short)0 : f2bf(hv[ii]);
        }
        // gy[0] = bias + y0@Wih^T
        {
            Frag yc0, yc1;
            yc0.s = *(const s16x8*)&ybuf[0][0][lane & 7][8*q];
            yc1.s = *(const s16x8*)&ybuf[0][0][lane & 7][32 + 8*q];
#pragma unroll
            for (int a = 0; a < 4; ++a) {
                f32x4 g = (f32x4){biasv[a], biasv[a], biasv[a], biasv[a]};
                g = mfma16(yc0.b, wfi[a][0].b, g);
                g = mfma16(yc1.b, wfi[a][1].b, g);
                gyr[a] = g;
            }
        }
    }
    block_sync_lds();   // #3: hbuf[0] visible

    // ---------------- main loop: 16 chunks x 8 phases ----------------
    for (int tc = 0; tc < 16; ++tc) {
#pragma unroll
        for (int p = 0; p < 8; ++p) {
            const int t = 8*tc + p;
            if (crit) {
                const int jcol = 16*w + c;
                const int cur = p & 1;
                Frag hf0, hf1;
                hf0.s = *(const s16x8*)&hbuf[cur][lane & 7][8*q];
                hf1.s = *(const s16x8*)&hbuf[cur][lane & 7][32 + 8*q];
                f32x4 acc[4];
#pragma unroll
                for (int a = 0; a < 4; ++a) {
                    acc[a] = mfma16(hf0.b, wf[a][0].b, gyr[a]);
                    acc[a] = mfma16(hf1.b, wf[a][1].b, acc[a]);
                }
                const bool hiq = (q >= 2);
                float g0[4], g1[4];
#pragma unroll
                for (int a = 0; a < 4; ++a) {
                    g0[a] = hiq ? acc[a][2] : acc[a][0];
                    g1[a] = hiq ? acc[a][3] : acc[a][1];
                }
                const float dn0 = dbuf[t+1][r0 + 0];
                const float dn1 = dbuf[t+1][r0 + 1];
                // gy[t+1] refill (hides under ELEM on MFMA pipe)
                if (tc < 15 || p < 7) {
                    const int ch = (p < 7) ? (tc & 1) : ((tc + 1) & 1);
                    const int sl = (p + 1) & 7;
                    Frag yc0, yc1;
                    yc0.s = *(const s16x8*)&ybuf[ch][sl][lane & 7][8*q];
                    yc1.s = *(const s16x8*)&ybuf[ch][sl][lane & 7][32 + 8*q];
#pragma unroll
                    for (int a = 0; a < 4; ++a) {
                        f32x4 g = (f32x4){biasv[a], biasv[a], biasv[a], biasv[a]};
                        g = mfma16(yc0.b, wfi[a][0].b, g);
                        g = mfma16(yc1.b, wfi[a][1].b, g);
                        gyr[a] = g;
                    }
                }
#define ELEM(GV, CSTV, RI, DN) {                                        \
                float ei = __expf(-GV[0]), ef = __expf(-GV[1]);         \
                float eg = __expf(-2.0f*GV[2]), eo = __expf(-GV[3]);    \
                float term = (1.0f - eg) * fast_rcp((1.0f + ei)*(1.0f + eg)); \
                float cn = fast_rcp(1.0f + ef)*CSTV + term;             \
                float ec = __expf(-2.0f*cn);                            \
                float hv = (1.0f - ec) * fast_rcp((1.0f + eo)*(1.0f + ec)); \
                short zb = f2bf(hv);                                    \
                zbuf[cur][RI][jcol] = zb;                               \
                const bool d = ((DN) != 0.0f);                          \
                CSTV = d ? 0.0f : cn;                                   \
                hbuf[cur ^ 1][RI][jcol] = d ? (short)0 : zb; }
                ELEM(g0, cst0, r0 + 0, dn0)
                ELEM(g1, cst1, r0 + 1, dn1)
#undef ELEM
            } else {
                // ---- helper MLP pipeline for chunk tc+1 (x staged 1 chunk ago) ----
                if (p == 0 && tc <= 13) {          // stage x for chunk tc+2
#pragma unroll
                    for (int i = 0; i < 2; ++i)
                        stage_x(x, 8*(tc+2) + 2*hw + i, b0, lane,
                                &xbuf[tc & 1][2*hw + i][0][0]);
                }
                if (p == 1 && tc < 15) mlp_l1(&xbuf[(tc+1) & 1][2*hw + 0][0][0], b1v, w1t, lane, c, q, acc1);
                if (p == 2 && tc < 15) mlp_mid(acc1, c1buf[hw], c, q, a2f);
                if (p == 3 && tc < 15) mlp_l2(a2f, b2v, w2t, ybuf[(tc+1) & 1][2*hw + 0], c, q);
                if (p == 4 && tc < 15) mlp_l1(&xbuf[(tc+1) & 1][2*hw + 1][0][0], b1v, w1t, lane, c, q, acc1);
                if (p == 5 && tc < 15) mlp_mid(acc1, c1buf[hw], c, q, a2f);
                if (p == 6 && tc < 15) mlp_l2(a2f, b2v, w2t, ybuf[(tc+1) & 1][2*hw + 1], c, q);
                if (p == 7) {
                    __builtin_amdgcn_s_waitcnt(0x0F70);   // drain GLDS (7-phase lead)
                    if (tc >= 1 && w == 4) {               // flush chunk tc-1 outputs
                        const int cc = tc - 1;
                        const int s = lane >> 3, r = lane & 7;
                        const size_t row = (size_t)(8*cc + s)*BB + b0 + r;
                        const float* ob = &obuf[cc & 1][s][r][0];
                        float* lp = out_logits + row*AA;
#pragma unroll
                        for (int n = 0; n < 15; ++n) lp[n] = ob[n];
                        out_vf[row] = ob[15];
                    }
                }
                // ---- head duty for z[t-1] ----
                if ((tc > 0 || p > 0) && w == 4 + (p & 3)) {
                    const int tp = t - 1;
                    Frag zf0, zf1;
                    zf0.s = *(const s16x8*)&zbuf[tp & 1][lane & 7][8*q];
                    zf1.s = *(const s16x8*)&zbuf[tp & 1][lane & 7][32 + 8*q];
                    f32x4 ha = (f32x4){hbv, hbv, hbv, hbv};
                    ha = mfma16(zf0.b, hwf[0].b, ha);
                    ha = mfma16(zf1.b, hwf[1].b, ha);
                    if (q < 2) {
#pragma unroll
                        for (int i = 0; i < 4; ++i)
                            obuf[(tp >> 3) & 1][tp & 7][4*q + i][c] = ha[i];
                    }
                }
            }
            block_sync_lds();
        }
    }

    // ---------------- epilogue ----------------
    if (!crit && w == 7) {                         // head for z[127]
        Frag zf0, zf1;
        zf0.s = *(const s16x8*)&zbuf[1][lane & 7][8*q];
        zf1.s = *(const s16x8*)&zbuf[1][lane & 7][32 + 8*q];
        f32x4 ha = (f32x4){hbv, hbv, hbv, hbv};
        ha = mfma16(zf0.b, hwf[0].b, ha);
        ha = mfma16(zf1.b, hwf[1].b, ha);
        if (q < 2) {
#pragma unroll
            for (int i = 0; i < 4; ++i) obuf[1][7][4*q + i][c] = ha[i];
        }
    }
    __syncthreads();
    if (!crit && w == 4) {                         // flush chunk 15
        const int s = lane >> 3, r = lane & 7;
        const size_t row = (size_t)(120 + s)*BB + b0 + r;
        const float* ob = &obuf[1][s][r][0];
        float* lp = out_logits + row*AA;
#pragma unroll
        for (int n = 0; n < 15; ++n) lp[n] = ob[n];
        out_vf[row] = ob[15];
    }
    if (tid < 128) {                               // hT = z127
        int mm = tid & 7, j4 = (tid >> 3) & 15;
        f32x4 hv;
#pragma unroll
        for (int ii = 0; ii < 4; ++ii) hv[ii] = bf2f(zbuf[1][mm][4*j4 + ii]);
        *(f32x4*)(hT_out + (size_t)(b0 + mm)*HH + 4*j4) = hv;
    }
    if (crit) {
        const int jcol = 16*w + c;
        cT_out[(size_t)(b0 + r0 + 0)*HH + jcol] = cst0;
        cT_out[(size_t)(b0 + r0 + 1)*HH + jcol] = cst1;
    }
}

// ============================ launch ============================
extern "C" void kernel_launch(void* const* d_in, const int* in_sizes, int n_in,
                              void* d_out, int out_size, void* d_ws, size_t ws_size,
                              hipStream_t stream) {
    const float* x    = (const float*)d_in[0];
    const float* done = (const float*)d_in[1];
    const float* h0   = (const float*)d_in[2];
    const float* c0   = (const float*)d_in[3];
    const float* W1   = (const float*)d_in[4];
    const float* b1   = (const float*)d_in[5];
    const float* W2   = (const float*)d_in[6];
    const float* b2   = (const float*)d_in[7];
    const float* Wih  = (const float*)d_in[8];
    const float* bih  = (const float*)d_in[9];
    const float* Whh  = (const float*)d_in[10];
    const float* bhh  = (const float*)d_in[11];
    const float* Wa   = (const float*)d_in[12];
    const float* ba   = (const float*)d_in[13];
    const float* Wc   = (const float*)d_in[14];
    const float* bc   = (const float*)d_in[15];
    float* out = (float*)d_out;

    (void)d_ws; (void)ws_size;   // no workspace: fused single-kernel pipeline

    fused_kernel<<<256, 512, 0, stream>>>(x, done, h0, c0, W1, b1, W2, b2,
                                          Wih, bih, Whh, bhh, Wa, ba, Wc, bc,
                                          out + LOGITS_OFF, out + VF_OFF,
                                          out + HT_OFF, out + CT_OFF);
}